// Round 3
// baseline (96.911 us; speedup 1.0000x reference)
//
#include <hip/hip_runtime.h>

// Problem constants (from reference: N=8192, M=100000, K=4096)
#define K_TOTAL 4096
#define N_RAYS  8192
#define S_CHUNKS 32
#define CHUNK (K_TOTAL / S_CHUNKS)   // 128 gaussians per K-chunk

// ---------------------------------------------------------------------------
// Kernel 1: per-selected-gaussian precompute.
// For each k: i = idx[k]; L = chol[i] (lower-tri, positive diag);
// Sigma = L L^T ; Sigma_inv = (L^-1)^T (L^-1) via forward substitution.
// Fold -0.5 (from exp(-0.5 q)), the off-diagonal x2 symmetry factor, and
// log2(e) (so the hot loop can use v_exp_f32 = exp2) into coefficients.
// Table layout per k (4 x float4 = 64 B):
//   t0 = (mu0, mu1, mu2, mu3)
//   t1 = (c00, c11, c22, c33)          c_ii = -0.5*log2e*Sinv_ii
//   t2 = (c01, c02, c03, c12)          c_ij = -log2e*Sinv_ij   (i<j)
//   t3 = (c13, c23, label, 0)
// ---------------------------------------------------------------------------
__global__ __launch_bounds__(256) void precompute_kernel(
    const float* __restrict__ embeddings,
    const float* __restrict__ chol,
    const float* __restrict__ labels,
    const int*   __restrict__ idx,
    float4*      __restrict__ tab)
{
    int k = blockIdx.x * blockDim.x + threadIdx.x;
    if (k >= K_TOTAL) return;
    int i = idx[k];

    const float* Lp = chol + (size_t)i * 16;
    float l00 = Lp[0];
    float l10 = Lp[4],  l11 = Lp[5];
    float l20 = Lp[8],  l21 = Lp[9],  l22 = Lp[10];
    float l30 = Lp[12], l31 = Lp[13], l32 = Lp[14], l33 = Lp[15];

    float u0 = 1.0f / l00, u1 = 1.0f / l11, u2 = 1.0f / l22, u3 = 1.0f / l33;

    // M = L^-1 (lower triangular), forward substitution
    float m00 = u0;
    float m10 = -u1 * (l10 * m00);
    float m11 = u1;
    float m20 = -u2 * (l20 * m00 + l21 * m10);
    float m21 = -u2 * (l21 * m11);
    float m22 = u2;
    float m30 = -u3 * (l30 * m00 + l31 * m10 + l32 * m20);
    float m31 = -u3 * (l31 * m11 + l32 * m21);
    float m32 = -u3 * (l32 * m22);
    float m33 = u3;

    // Sinv = M^T M (symmetric)
    float s00 = m00*m00 + m10*m10 + m20*m20 + m30*m30;
    float s01 = m10*m11 + m20*m21 + m30*m31;
    float s02 = m20*m22 + m30*m32;
    float s03 = m30*m33;
    float s11 = m11*m11 + m21*m21 + m31*m31;
    float s12 = m21*m22 + m31*m32;
    float s13 = m31*m33;
    float s22 = m22*m22 + m32*m32;
    float s23 = m32*m33;
    float s33 = m33*m33;

    const float CD = -0.72134752044448170368f;  // -0.5 * log2(e)
    const float CO = -1.44269504088896340736f;  // -1.0 * log2(e)

    float4 mu = *(const float4*)(embeddings + (size_t)i * 4);
    float lab = labels[i];

    tab[4*k + 0] = mu;
    tab[4*k + 1] = make_float4(CD*s00, CD*s11, CD*s22, CD*s33);
    tab[4*k + 2] = make_float4(CO*s01, CO*s02, CO*s03, CO*s12);
    tab[4*k + 3] = make_float4(CO*s13, CO*s23, lab, 0.0f);
}

// ---------------------------------------------------------------------------
// Kernel 2: main N x K pair loop.
// grid = (N/256 ray-blocks, S_CHUNKS k-chunks), block = 256 (1 ray/thread).
// Per-k table loads are wave-uniform (loop counter + blockIdx only) -> cheap
// (L1/L2-resident 8 KB per chunk), keeping the VALU pipe on the quadratic
// form + exp2.
// ---------------------------------------------------------------------------
__global__ __launch_bounds__(256) void main_kernel(
    const float*  __restrict__ origins,
    const float*  __restrict__ directions,
    const float4* __restrict__ tab,
    float*        __restrict__ partial)
{
    int n = blockIdx.x * 256 + threadIdx.x;
    int s = blockIdx.y;

    float2 o = ((const float2*)origins)[n];
    float2 d = ((const float2*)directions)[n];
    float p0 = o.x, p1 = o.y, p2 = d.x, p3 = d.y;

    const float4* __restrict__ t = tab + (size_t)s * CHUNK * 4;

    float acc = 0.0f;
    #pragma unroll 4
    for (int k = 0; k < CHUNK; ++k) {
        float4 t0 = t[4*k + 0];
        float4 t1 = t[4*k + 1];
        float4 t2 = t[4*k + 2];
        float4 t3 = t[4*k + 3];
        float d0 = p0 - t0.x;
        float d1 = p1 - t0.y;
        float d2 = p2 - t0.z;
        float d3 = p3 - t0.w;
        float e;
        e = t1.x * (d0 * d0);
        e = fmaf(t1.y, d1 * d1, e);
        e = fmaf(t1.z, d2 * d2, e);
        e = fmaf(t1.w, d3 * d3, e);
        e = fmaf(t2.x, d0 * d1, e);
        e = fmaf(t2.y, d0 * d2, e);
        e = fmaf(t2.z, d0 * d3, e);
        e = fmaf(t2.w, d1 * d2, e);
        e = fmaf(t3.x, d1 * d3, e);
        e = fmaf(t3.y, d2 * d3, e);
        // e <= 0 always (Sinv is SPD), so exp2(e) in (0,1]
        acc = fmaf(t3.z, __builtin_amdgcn_exp2f(e), acc);
    }
    partial[s * N_RAYS + n] = acc;
}

// ---------------------------------------------------------------------------
// Kernel 3: reduce the S_CHUNKS partials per ray + sigmoid.
// sigmoid(x) = 1 / (1 + exp2(-x * log2e))
// ---------------------------------------------------------------------------
__global__ __launch_bounds__(256) void finish_kernel(
    const float* __restrict__ partial,
    float*       __restrict__ out)
{
    int n = blockIdx.x * 256 + threadIdx.x;
    float sum = 0.0f;
    #pragma unroll
    for (int s = 0; s < S_CHUNKS; ++s)
        sum += partial[s * N_RAYS + n];
    const float L2E = 1.44269504088896340736f;
    out[n] = 1.0f / (1.0f + __builtin_amdgcn_exp2f(-sum * L2E));
}

extern "C" void kernel_launch(void* const* d_in, const int* in_sizes, int n_in,
                              void* d_out, int out_size, void* d_ws, size_t ws_size,
                              hipStream_t stream) {
    const float* origins    = (const float*)d_in[0];
    const float* directions = (const float*)d_in[1];
    const float* embeddings = (const float*)d_in[2];
    const float* chol       = (const float*)d_in[3];
    const float* labels     = (const float*)d_in[4];
    const int*   idx        = (const int*)d_in[5];
    float* out = (float*)d_out;

    // workspace layout: [table: 4096*4 float4 = 256 KB][partials: 32*8192 float = 1 MB]
    float4* tab     = (float4*)d_ws;
    float*  partial = (float*)((char*)d_ws + (size_t)K_TOTAL * 4 * sizeof(float4));

    precompute_kernel<<<dim3(K_TOTAL / 256), dim3(256), 0, stream>>>(
        embeddings, chol, labels, idx, tab);

    main_kernel<<<dim3(N_RAYS / 256, S_CHUNKS), dim3(256), 0, stream>>>(
        origins, directions, tab, partial);

    finish_kernel<<<dim3(N_RAYS / 256), dim3(256), 0, stream>>>(partial, out);
}

// Round 4
// 93.193 us; speedup vs baseline: 1.0399x; 1.0399x over previous
//
#include <hip/hip_runtime.h>
#include <math.h>

// Problem constants (from reference: N=8192, M=100000, K=4096)
#define K_TOTAL 4096
#define N_RAYS  8192
#define S_CHUNKS 128
#define CHUNK (K_TOTAL / S_CHUNKS)     // 32 gaussians per K-chunk
#define R 4                            // rays per thread (register tile)
#define BLOCK 256
#define RAYS_PER_BLOCK (BLOCK * R)     // 1024
#define NGROUPS (N_RAYS / RAYS_PER_BLOCK)  // 8

// ---------------------------------------------------------------------------
// Kernel 1: per-selected-gaussian precompute.
// i = idx[k]; L = chol[i] (lower-tri, +diag). Sigma = L L^T, so
// Sigma_inv = M^T M with M = L^-1 (forward substitution).
// q = diff^T Sinv diff = ||M diff||^2. Fold sqrt(0.5*log2e) into M (-> M')
// and precompute b = -M'*mu, so the hot loop computes y = M'*p + b and
// e = exp2(-||y||^2) — 10 FMA + 4 sumsq + free-neg exp2 per pair.
// Table layout per k (4 x float4 = 64 B):
//   t0 = (m00, m10, m11, m20)   (scaled M' entries, row-major lower tri)
//   t1 = (m21, m22, m30, m31)
//   t2 = (m32, m33, b0,  b1 )
//   t3 = (b2,  b3,  lab, 0  )
// ---------------------------------------------------------------------------
__global__ __launch_bounds__(256) void precompute_kernel(
    const float* __restrict__ embeddings,
    const float* __restrict__ chol,
    const float* __restrict__ labels,
    const int*   __restrict__ idx,
    float4*      __restrict__ tab)
{
    int k = blockIdx.x * blockDim.x + threadIdx.x;
    if (k >= K_TOTAL) return;
    int i = idx[k];

    const float* Lp = chol + (size_t)i * 16;
    float l00 = Lp[0];
    float l10 = Lp[4],  l11 = Lp[5];
    float l20 = Lp[8],  l21 = Lp[9],  l22 = Lp[10];
    float l30 = Lp[12], l31 = Lp[13], l32 = Lp[14], l33 = Lp[15];

    float u0 = 1.0f / l00, u1 = 1.0f / l11, u2 = 1.0f / l22, u3 = 1.0f / l33;

    // M = L^-1 (lower triangular), forward substitution
    float m00 = u0;
    float m10 = -u1 * (l10 * m00);
    float m11 = u1;
    float m20 = -u2 * (l20 * m00 + l21 * m10);
    float m21 = -u2 * (l21 * m11);
    float m22 = u2;
    float m30 = -u3 * (l30 * m00 + l31 * m10 + l32 * m20);
    float m31 = -u3 * (l31 * m11 + l32 * m21);
    float m32 = -u3 * (l32 * m22);
    float m33 = u3;

    // scale by sqrt(0.5 * log2(e)) so exp(-0.5 q) == exp2(-||M' diff||^2)
    const float SC = 0.84932180381996511548f;  // sqrt(0.72134752044448170368)
    m00 *= SC; m10 *= SC; m11 *= SC; m20 *= SC; m21 *= SC;
    m22 *= SC; m30 *= SC; m31 *= SC; m32 *= SC; m33 *= SC;

    float4 mu = *(const float4*)(embeddings + (size_t)i * 4);
    float b0 = -(m00 * mu.x);
    float b1 = -(m10 * mu.x + m11 * mu.y);
    float b2 = -(m20 * mu.x + m21 * mu.y + m22 * mu.z);
    float b3 = -(m30 * mu.x + m31 * mu.y + m32 * mu.z + m33 * mu.w);

    float lab = labels[i];

    tab[4*k + 0] = make_float4(m00, m10, m11, m20);
    tab[4*k + 1] = make_float4(m21, m22, m30, m31);
    tab[4*k + 2] = make_float4(m32, m33, b0, b1);
    tab[4*k + 3] = make_float4(b2, b3, lab, 0.0f);
}

// ---------------------------------------------------------------------------
// Kernel 2: main N x K pair loop, register-tiled R=4 rays/thread.
// grid = (NGROUPS, S_CHUNKS), block = 256. Table loads are wave-uniform and
// amortized over 4 rays; 4 independent dep chains give ILP at 4 blocks/CU.
// ---------------------------------------------------------------------------
__global__ __launch_bounds__(256) void main_kernel(
    const float*  __restrict__ origins,
    const float*  __restrict__ directions,
    const float4* __restrict__ tab,
    float*        __restrict__ partial)
{
    int tid  = threadIdx.x;
    int base = blockIdx.x * RAYS_PER_BLOCK + tid;   // ray of lane for r=0
    int s    = blockIdx.y;

    float p0[R], p1[R], p2[R], p3[R], acc[R];
    #pragma unroll
    for (int r = 0; r < R; ++r) {
        int n = base + r * BLOCK;
        float2 o = ((const float2*)origins)[n];
        float2 d = ((const float2*)directions)[n];
        p0[r] = o.x; p1[r] = o.y; p2[r] = d.x; p3[r] = d.y;
        acc[r] = 0.0f;
    }

    const float4* __restrict__ t = tab + (size_t)s * CHUNK * 4;

    #pragma unroll 4
    for (int k = 0; k < CHUNK; ++k) {
        float4 t0 = t[4*k + 0];
        float4 t1 = t[4*k + 1];
        float4 t2 = t[4*k + 2];
        float4 t3 = t[4*k + 3];
        // t0 = (m00,m10,m11,m20) t1 = (m21,m22,m30,m31)
        // t2 = (m32,m33,b0,b1)   t3 = (b2,b3,lab,-)
        #pragma unroll
        for (int r = 0; r < R; ++r) {
            float y0 = fmaf(t0.x, p0[r], t2.z);
            float y1 = fmaf(t0.z, p1[r], fmaf(t0.y, p0[r], t2.w));
            float y2 = fmaf(t1.y, p2[r], fmaf(t1.x, p1[r], fmaf(t0.w, p0[r], t3.x)));
            float y3 = fmaf(t2.y, p3[r], fmaf(t2.x, p2[r], fmaf(t1.w, p1[r], fmaf(t1.z, p0[r], t3.y))));
            float sq = y0 * y0;
            sq = fmaf(y1, y1, sq);
            sq = fmaf(y2, y2, sq);
            sq = fmaf(y3, y3, sq);
            acc[r] = fmaf(t3.z, __builtin_amdgcn_exp2f(-sq), acc[r]);
        }
    }

    #pragma unroll
    for (int r = 0; r < R; ++r)
        partial[(size_t)s * N_RAYS + base + r * BLOCK] = acc[r];
}

// ---------------------------------------------------------------------------
// Kernel 3: reduce the S_CHUNKS partials per ray + sigmoid.
// sigmoid(x) = 1 / (1 + exp2(-x * log2e))
// ---------------------------------------------------------------------------
__global__ __launch_bounds__(256) void finish_kernel(
    const float* __restrict__ partial,
    float*       __restrict__ out)
{
    int n = blockIdx.x * 256 + threadIdx.x;
    float sum = 0.0f;
    #pragma unroll 8
    for (int s = 0; s < S_CHUNKS; ++s)
        sum += partial[(size_t)s * N_RAYS + n];
    const float L2E = 1.44269504088896340736f;
    out[n] = 1.0f / (1.0f + __builtin_amdgcn_exp2f(-sum * L2E));
}

extern "C" void kernel_launch(void* const* d_in, const int* in_sizes, int n_in,
                              void* d_out, int out_size, void* d_ws, size_t ws_size,
                              hipStream_t stream) {
    const float* origins    = (const float*)d_in[0];
    const float* directions = (const float*)d_in[1];
    const float* embeddings = (const float*)d_in[2];
    const float* chol       = (const float*)d_in[3];
    const float* labels     = (const float*)d_in[4];
    const int*   idx        = (const int*)d_in[5];
    float* out = (float*)d_out;

    // workspace: [table: 4096*4 float4 = 256 KB][partials: 128*8192 float = 4 MB]
    float4* tab     = (float4*)d_ws;
    float*  partial = (float*)((char*)d_ws + (size_t)K_TOTAL * 4 * sizeof(float4));

    precompute_kernel<<<dim3(K_TOTAL / 256), dim3(256), 0, stream>>>(
        embeddings, chol, labels, idx, tab);

    main_kernel<<<dim3(NGROUPS, S_CHUNKS), dim3(256), 0, stream>>>(
        origins, directions, tab, partial);

    finish_kernel<<<dim3(N_RAYS / 256), dim3(256), 0, stream>>>(partial, out);
}

// Round 5
// 89.002 us; speedup vs baseline: 1.0889x; 1.0471x over previous
//
#include <hip/hip_runtime.h>
#include <math.h>

// Problem constants (from reference: N=8192, M=100000, K=4096)
#define K_TOTAL 4096
#define N_RAYS  8192
#define S_CHUNKS 128
#define CHUNK (K_TOTAL / S_CHUNKS)     // 32 gaussians per K-chunk
#define R 4                            // rays per thread (register tile)
#define BLOCK 256
#define RAYS_PER_BLOCK (BLOCK * R)     // 1024
#define NGROUPS (N_RAYS / RAYS_PER_BLOCK)  // 8

// ---------------------------------------------------------------------------
// Fused kernel: per-chunk table precompute (in LDS) + main pair loop.
//
// Precompute (first CHUNK threads of each block): i = idx[k]; L = chol[i]
// (lower-tri, +diag). Sigma = L L^T -> Sigma_inv = M^T M, M = L^-1 (forward
// substitution). q = ||M diff||^2. Fold sqrt(0.5*log2e) into M (-> M') and
// b = -M'*mu, so the hot loop computes y = M'*p + b, e = exp2(-||y||^2):
// 10 FMA + 4 sumsq + free-neg exp2 + 1 acc FMA per pair.
//
// Each block redundantly computes its own 32-entry chunk table (8x redundancy
// across x-groups, trivial work, L2-absorbed gathers) — saves a separate
// kernel launch and the table's global-memory round-trip.
//
// LDS layout per k (4 x float4 = 64 B):
//   t0 = (m00, m10, m11, m20)   t1 = (m21, m22, m30, m31)
//   t2 = (m32, m33, b0,  b1 )   t3 = (b2,  b3,  lab, 0  )
// Main-loop LDS reads are wave-uniform -> broadcast, conflict-free.
// ---------------------------------------------------------------------------
__global__ __launch_bounds__(256) void fused_main_kernel(
    const float* __restrict__ origins,
    const float* __restrict__ directions,
    const float* __restrict__ embeddings,
    const float* __restrict__ chol,
    const float* __restrict__ labels,
    const int*   __restrict__ idx,
    float*       __restrict__ partial)
{
    __shared__ float4 stab[CHUNK * 4];   // 2 KB

    int tid = threadIdx.x;
    int s   = blockIdx.y;

    if (tid < CHUNK) {
        int k = s * CHUNK + tid;
        int i = idx[k];

        const float* Lp = chol + (size_t)i * 16;
        float l00 = Lp[0];
        float l10 = Lp[4],  l11 = Lp[5];
        float l20 = Lp[8],  l21 = Lp[9],  l22 = Lp[10];
        float l30 = Lp[12], l31 = Lp[13], l32 = Lp[14], l33 = Lp[15];

        float u0 = 1.0f / l00, u1 = 1.0f / l11, u2 = 1.0f / l22, u3 = 1.0f / l33;

        // M = L^-1 (lower triangular), forward substitution
        float m00 = u0;
        float m10 = -u1 * (l10 * m00);
        float m11 = u1;
        float m20 = -u2 * (l20 * m00 + l21 * m10);
        float m21 = -u2 * (l21 * m11);
        float m22 = u2;
        float m30 = -u3 * (l30 * m00 + l31 * m10 + l32 * m20);
        float m31 = -u3 * (l31 * m11 + l32 * m21);
        float m32 = -u3 * (l32 * m22);
        float m33 = u3;

        // scale by sqrt(0.5 * log2(e)) so exp(-0.5 q) == exp2(-||M' diff||^2)
        const float SC = 0.84932180381996511548f;
        m00 *= SC; m10 *= SC; m11 *= SC; m20 *= SC; m21 *= SC;
        m22 *= SC; m30 *= SC; m31 *= SC; m32 *= SC; m33 *= SC;

        float4 mu = *(const float4*)(embeddings + (size_t)i * 4);
        float b0 = -(m00 * mu.x);
        float b1 = -(m10 * mu.x + m11 * mu.y);
        float b2 = -(m20 * mu.x + m21 * mu.y + m22 * mu.z);
        float b3 = -(m30 * mu.x + m31 * mu.y + m32 * mu.z + m33 * mu.w);

        float lab = labels[i];

        stab[tid*4 + 0] = make_float4(m00, m10, m11, m20);
        stab[tid*4 + 1] = make_float4(m21, m22, m30, m31);
        stab[tid*4 + 2] = make_float4(m32, m33, b0, b1);
        stab[tid*4 + 3] = make_float4(b2, b3, lab, 0.0f);
    }

    int base = blockIdx.x * RAYS_PER_BLOCK + tid;   // ray of lane for r=0

    float p0[R], p1[R], p2[R], p3[R], acc[R];
    #pragma unroll
    for (int r = 0; r < R; ++r) {
        int n = base + r * BLOCK;
        float2 o = ((const float2*)origins)[n];
        float2 d = ((const float2*)directions)[n];
        p0[r] = o.x; p1[r] = o.y; p2[r] = d.x; p3[r] = d.y;
        acc[r] = 0.0f;
    }

    __syncthreads();

    #pragma unroll 8
    for (int k = 0; k < CHUNK; ++k) {
        float4 t0 = stab[k*4 + 0];
        float4 t1 = stab[k*4 + 1];
        float4 t2 = stab[k*4 + 2];
        float4 t3 = stab[k*4 + 3];
        #pragma unroll
        for (int r = 0; r < R; ++r) {
            float y0 = fmaf(t0.x, p0[r], t2.z);
            float y1 = fmaf(t0.z, p1[r], fmaf(t0.y, p0[r], t2.w));
            float y2 = fmaf(t1.y, p2[r], fmaf(t1.x, p1[r], fmaf(t0.w, p0[r], t3.x)));
            float y3 = fmaf(t2.y, p3[r], fmaf(t2.x, p2[r], fmaf(t1.w, p1[r], fmaf(t1.z, p0[r], t3.y))));
            float sq = y0 * y0;
            sq = fmaf(y1, y1, sq);
            sq = fmaf(y2, y2, sq);
            sq = fmaf(y3, y3, sq);
            acc[r] = fmaf(t3.z, __builtin_amdgcn_exp2f(-sq), acc[r]);
        }
    }

    #pragma unroll
    for (int r = 0; r < R; ++r)
        partial[(size_t)s * N_RAYS + base + r * BLOCK] = acc[r];
}

// ---------------------------------------------------------------------------
// Finish: reduce the S_CHUNKS partials per ray + sigmoid.
// 128 blocks x 64 threads -> 128 CUs engaged; unrolled independent loads
// keep many outstanding to hide L2 latency.
// sigmoid(x) = 1 / (1 + exp2(-x * log2e))
// ---------------------------------------------------------------------------
__global__ __launch_bounds__(64) void finish_kernel(
    const float* __restrict__ partial,
    float*       __restrict__ out)
{
    int n = blockIdx.x * 64 + threadIdx.x;
    float sum = 0.0f;
    #pragma unroll 16
    for (int s = 0; s < S_CHUNKS; ++s)
        sum += partial[(size_t)s * N_RAYS + n];
    const float L2E = 1.44269504088896340736f;
    out[n] = 1.0f / (1.0f + __builtin_amdgcn_exp2f(-sum * L2E));
}

extern "C" void kernel_launch(void* const* d_in, const int* in_sizes, int n_in,
                              void* d_out, int out_size, void* d_ws, size_t ws_size,
                              hipStream_t stream) {
    const float* origins    = (const float*)d_in[0];
    const float* directions = (const float*)d_in[1];
    const float* embeddings = (const float*)d_in[2];
    const float* chol       = (const float*)d_in[3];
    const float* labels     = (const float*)d_in[4];
    const int*   idx        = (const int*)d_in[5];
    float* out = (float*)d_out;

    // workspace: [partials: 128*8192 float = 4 MB]
    float* partial = (float*)d_ws;

    fused_main_kernel<<<dim3(NGROUPS, S_CHUNKS), dim3(BLOCK), 0, stream>>>(
        origins, directions, embeddings, chol, labels, idx, partial);

    finish_kernel<<<dim3(N_RAYS / 64), dim3(64), 0, stream>>>(partial, out);
}

// Round 6
// 87.206 us; speedup vs baseline: 1.1113x; 1.0206x over previous
//
#include <hip/hip_runtime.h>
#include <math.h>

// Problem constants (from reference: N=8192, M=100000, K=4096)
#define K_TOTAL 4096
#define N_RAYS  8192
#define S_CHUNKS 128
#define CHUNK (K_TOTAL / S_CHUNKS)     // 32 gaussians per K-chunk
#define R 4                            // rays per thread (register tile)
#define BLOCK 256
#define RAYS_PER_BLOCK (BLOCK * R)     // 1024
#define NGROUPS (N_RAYS / RAYS_PER_BLOCK)  // 8

// ---------------------------------------------------------------------------
// Fused kernel: per-chunk table precompute (in LDS) + main pair loop.
// Sigma = L L^T -> Sigma_inv = M^T M, M = L^-1 (forward substitution).
// q = ||M diff||^2; fold sqrt(0.5*log2e) into M (-> M'), b = -M'*mu, so the
// hot loop is y = M'*p + b, e = exp2(-||y||^2): 15 VALU + 1 trans per pair.
// LDS reads are wave-uniform -> broadcast, conflict-free.
// __launch_bounds__(256,4): cap VGPR <= 128 so 4 blocks/CU (16 waves/CU)
// stay co-resident — latency hiding for the LDS reads + exp chain.
// ---------------------------------------------------------------------------
__global__ __launch_bounds__(256, 4) void fused_main_kernel(
    const float* __restrict__ origins,
    const float* __restrict__ directions,
    const float* __restrict__ embeddings,
    const float* __restrict__ chol,
    const float* __restrict__ labels,
    const int*   __restrict__ idx,
    float*       __restrict__ partial)
{
    __shared__ float4 stab[CHUNK * 4];   // 2 KB

    int tid = threadIdx.x;
    int s   = blockIdx.y;

    if (tid < CHUNK) {
        int k = s * CHUNK + tid;
        int i = idx[k];

        const float* Lp = chol + (size_t)i * 16;
        float l00 = Lp[0];
        float l10 = Lp[4],  l11 = Lp[5];
        float l20 = Lp[8],  l21 = Lp[9],  l22 = Lp[10];
        float l30 = Lp[12], l31 = Lp[13], l32 = Lp[14], l33 = Lp[15];

        float u0 = 1.0f / l00, u1 = 1.0f / l11, u2 = 1.0f / l22, u3 = 1.0f / l33;

        // M = L^-1 (lower triangular), forward substitution
        float m00 = u0;
        float m10 = -u1 * (l10 * m00);
        float m11 = u1;
        float m20 = -u2 * (l20 * m00 + l21 * m10);
        float m21 = -u2 * (l21 * m11);
        float m22 = u2;
        float m30 = -u3 * (l30 * m00 + l31 * m10 + l32 * m20);
        float m31 = -u3 * (l31 * m11 + l32 * m21);
        float m32 = -u3 * (l32 * m22);
        float m33 = u3;

        // scale by sqrt(0.5 * log2(e)) so exp(-0.5 q) == exp2(-||M' diff||^2)
        const float SC = 0.84932180381996511548f;
        m00 *= SC; m10 *= SC; m11 *= SC; m20 *= SC; m21 *= SC;
        m22 *= SC; m30 *= SC; m31 *= SC; m32 *= SC; m33 *= SC;

        float4 mu = *(const float4*)(embeddings + (size_t)i * 4);
        float b0 = -(m00 * mu.x);
        float b1 = -(m10 * mu.x + m11 * mu.y);
        float b2 = -(m20 * mu.x + m21 * mu.y + m22 * mu.z);
        float b3 = -(m30 * mu.x + m31 * mu.y + m32 * mu.z + m33 * mu.w);

        float lab = labels[i];

        stab[tid*4 + 0] = make_float4(m00, m10, m11, m20);
        stab[tid*4 + 1] = make_float4(m21, m22, m30, m31);
        stab[tid*4 + 2] = make_float4(m32, m33, b0, b1);
        stab[tid*4 + 3] = make_float4(b2, b3, lab, 0.0f);
    }

    int base = blockIdx.x * RAYS_PER_BLOCK + tid;   // ray of lane for r=0

    float p0[R], p1[R], p2[R], p3[R], acc[R];
    #pragma unroll
    for (int r = 0; r < R; ++r) {
        int n = base + r * BLOCK;
        float2 o = ((const float2*)origins)[n];
        float2 d = ((const float2*)directions)[n];
        p0[r] = o.x; p1[r] = o.y; p2[r] = d.x; p3[r] = d.y;
        acc[r] = 0.0f;
    }

    __syncthreads();

    #pragma unroll 8
    for (int k = 0; k < CHUNK; ++k) {
        float4 t0 = stab[k*4 + 0];
        float4 t1 = stab[k*4 + 1];
        float4 t2 = stab[k*4 + 2];
        float4 t3 = stab[k*4 + 3];
        #pragma unroll
        for (int r = 0; r < R; ++r) {
            float y0 = fmaf(t0.x, p0[r], t2.z);
            float y1 = fmaf(t0.z, p1[r], fmaf(t0.y, p0[r], t2.w));
            float y2 = fmaf(t1.y, p2[r], fmaf(t1.x, p1[r], fmaf(t0.w, p0[r], t3.x)));
            float y3 = fmaf(t2.y, p3[r], fmaf(t2.x, p2[r], fmaf(t1.w, p1[r], fmaf(t1.z, p0[r], t3.y))));
            float sq = y0 * y0;
            sq = fmaf(y1, y1, sq);
            sq = fmaf(y2, y2, sq);
            sq = fmaf(y3, y3, sq);
            acc[r] = fmaf(t3.z, __builtin_amdgcn_exp2f(-sq), acc[r]);
        }
    }

    #pragma unroll
    for (int r = 0; r < R; ++r)
        partial[(size_t)s * N_RAYS + base + r * BLOCK] = acc[r];
}

// ---------------------------------------------------------------------------
// Finish: reduce the S_CHUNKS partials per ray + sigmoid.
// Fully unrolled: 128 independent L2 loads in flight per thread (BW-bound,
// not latency-bound), pairwise tree sum. 128 blocks x 64 threads.
// sigmoid(x) = 1 / (1 + exp2(-x * log2e))
// ---------------------------------------------------------------------------
__global__ __launch_bounds__(64) void finish_kernel(
    const float* __restrict__ partial,
    float*       __restrict__ out)
{
    int n = blockIdx.x * 64 + threadIdx.x;
    float v[S_CHUNKS];
    #pragma unroll
    for (int s = 0; s < S_CHUNKS; ++s)
        v[s] = partial[(size_t)s * N_RAYS + n];
    // pairwise tree reduction (independent adds, log depth)
    #pragma unroll
    for (int w = S_CHUNKS / 2; w >= 1; w >>= 1)
        #pragma unroll
        for (int s = 0; s < w; ++s)
            v[s] += v[s + w];
    const float L2E = 1.44269504088896340736f;
    out[n] = 1.0f / (1.0f + __builtin_amdgcn_exp2f(-v[0] * L2E));
}

extern "C" void kernel_launch(void* const* d_in, const int* in_sizes, int n_in,
                              void* d_out, int out_size, void* d_ws, size_t ws_size,
                              hipStream_t stream) {
    const float* origins    = (const float*)d_in[0];
    const float* directions = (const float*)d_in[1];
    const float* embeddings = (const float*)d_in[2];
    const float* chol       = (const float*)d_in[3];
    const float* labels     = (const float*)d_in[4];
    const int*   idx        = (const int*)d_in[5];
    float* out = (float*)d_out;

    // workspace: [partials: 128*8192 float = 4 MB]
    float* partial = (float*)d_ws;

    fused_main_kernel<<<dim3(NGROUPS, S_CHUNKS), dim3(BLOCK), 0, stream>>>(
        origins, directions, embeddings, chol, labels, idx, partial);

    finish_kernel<<<dim3(N_RAYS / 64), dim3(64), 0, stream>>>(partial, out);
}